// Round 14
// baseline (86.115 us; speedup 1.0000x reference)
//
#include <hip/hip_runtime.h>
#include <hip/hip_bf16.h>

#define NL 10
#define NF 256
#define NNODE 257            // nodes per layer: u in [-16,16], h = 0.125
#define NENT (NL * NNODE)    // 2570 float4 entries = 41120 B
#define BLOCK 512

__device__ __forceinline__ float fexp2(float x) {
#if defined(__has_builtin)
#if __has_builtin(__builtin_amdgcn_exp2f)
  return __builtin_amdgcn_exp2f(x);
#else
  return exp2f(x);
#endif
#else
  return exp2f(x);
#endif
}

// ---------------------------------------------------------------------------
// Build per-layer lookup tables T[l][j] = {s, h*s', t, h*t'} at u_j = -16+j/8.
// Derivatives pre-scaled by h = 0.125 for Hermite evaluation.
// ---------------------------------------------------------------------------
__global__ __launch_bounds__(256) void build_table(
    const float* __restrict__ centers, const float* __restrict__ Ws,
    const float* __restrict__ Wt, const float* __restrict__ sigma,
    float4* __restrict__ T) {
  const int e = blockIdx.x * 256 + threadIdx.x;
  if (e >= NENT) return;
  const int l = e / NNODE;
  const int j = e - l * NNODE;
  const float u = -16.0f + 0.125f * (float)j;

  const float LOG2E = 1.4426950408889634f;
  const float sig = sigma[0];
  const float inv_s2 = 1.0f / (sig * sig);
  const float gl2 = -0.5f * inv_s2 * LOG2E;

  const float* __restrict__ c = centers + l * NF;
  const float* __restrict__ ws = Ws + l * NF;
  const float* __restrict__ wt = Wt + l * NF;
  float s = 0.f, t = 0.f, sp = 0.f, tp = 0.f;
  for (int i = 0; i < NF; ++i) {
    const float d = u - c[i];
    const float k = fexp2(gl2 * d * d);
    const float kd = k * d;
    s = fmaf(k, ws[i], s);
    t = fmaf(k, wt[i], t);
    sp = fmaf(kd, ws[i], sp);
    tp = fmaf(kd, wt[i], tp);
  }
  const float dscale = -inv_s2 * 0.125f;  // real-units deriv * h
  T[e] = make_float4(s, dscale * sp, t, dscale * tp);
}

// ---------------------------------------------------------------------------
// Exact attractor trajectory a = f(attr): one wave, 4 features/lane,
// butterfly-reduced per layer (the R2/R4/R10-validated wave-parallel form,
// on raw params — no interpolation error on `a`).
// ---------------------------------------------------------------------------
__global__ __launch_bounds__(64) void attractor_kernel(
    const float* __restrict__ centers, const float* __restrict__ Ws,
    const float* __restrict__ Wt, const float* __restrict__ attr,
    const float* __restrict__ sigma, float* __restrict__ a_out) {
  const int lane = threadIdx.x;
  const float LOG2E = 1.4426950408889634f;
  const float sig = sigma[0];
  const float inv_s2 = 1.0f / (sig * sig);
  const float gl2 = -0.5f * inv_s2 * LOG2E;

  float au = attr[0], av = attr[1];
  for (int l = 0; l < NL; ++l) {
    float s_p = 0.0f, t_p = 0.0f;
#pragma unroll
    for (int j = 0; j < 4; ++j) {
      const int f = l * NF + j * 64 + lane;
      const float d = au - centers[f];
      const float k = fexp2(gl2 * d * d);
      s_p = fmaf(k, Ws[f], s_p);
      t_p = fmaf(k, Wt[f], t_p);
    }
    for (int off = 32; off > 0; off >>= 1) {
      s_p += __shfl_xor(s_p, off);
      t_p += __shfl_xor(t_p, off);
    }
    const float E = fexp2(s_p * LOG2E);
    const float nav = fmaf(av, E, t_p);
    av = au;
    au = nav;
  }
  if (lane == 0) { a_out[0] = au; a_out[1] = av; }
}

// ---------------------------------------------------------------------------
// Main: one thread per point. Each layer step = cubic-Hermite table lookup
// (value + derivative of interpolant) + validated 2x2 Jacobian chain.
// ---------------------------------------------------------------------------
__global__ __launch_bounds__(BLOCK, 4) void dynamics_kernel(
    const float* __restrict__ x, const float4* __restrict__ Tg,
    const float* __restrict__ a_in, float* __restrict__ out, int npts) {
  __shared__ float4 T[NENT];  // 41.1 KiB
  const int tid = threadIdx.x;
  for (int i = tid; i < NENT; i += BLOCK) T[i] = Tg[i];
  __syncthreads();

  const float LOG2E = 1.4426950408889634f;

#define LAYER_STEP(lbase, u, v, Ju0, Ju1, Jv0, Jv1)                        \
  {                                                                        \
    const float pos = fmaf(u, 8.0f, 128.0f); /* (u+16)/h */                \
    const float jf = floorf(pos);                                          \
    int j = (int)jf;                                                       \
    j = j < 0 ? 0 : (j > NNODE - 2 ? NNODE - 2 : j);                       \
    const float tau = pos - (float)j;                                      \
    const bool uok = (pos >= 0.0f) && (pos <= 256.0f);                     \
    const float4 n0 = T[lbase + j];                                        \
    const float4 n1 = T[lbase + j + 1];                                    \
    const float t2 = tau * tau;                                            \
    const float t3 = t2 * tau;                                             \
    const float h00 = 2.f * t3 - 3.f * t2 + 1.f;                           \
    const float h10 = t3 - 2.f * t2 + tau;                                 \
    const float h01 = 3.f * t2 - 2.f * t3;                                 \
    const float h11 = t3 - t2;                                             \
    const float d00 = 6.f * t2 - 6.f * tau;                                \
    const float d10 = 3.f * t2 - 4.f * tau + 1.f;                          \
    const float d01 = 6.f * tau - 6.f * t2;                                \
    const float d11 = 3.f * t2 - 2.f * tau;                                \
    float sv = fmaf(h00, n0.x, fmaf(h10, n0.y, fmaf(h01, n1.x, h11 * n1.y))); \
    float tv = fmaf(h00, n0.z, fmaf(h10, n0.w, fmaf(h01, n1.z, h11 * n1.w))); \
    float sd = fmaf(d00, n0.x, fmaf(d10, n0.y, fmaf(d01, n1.x, d11 * n1.y))); \
    float td = fmaf(d00, n0.z, fmaf(d10, n0.w, fmaf(d01, n1.z, d11 * n1.w))); \
    sv = uok ? sv : 0.0f;  /* outside table: true values < 1e-15 */        \
    tv = uok ? tv : 0.0f;                                                  \
    sd = uok ? sd * 8.0f : 0.0f;  /* 1/h rescale to real units */          \
    td = uok ? td * 8.0f : 0.0f;                                           \
    const float E = fexp2(sv * LOG2E);                                     \
    const float g = fmaf(v * E, sd, td);                                   \
    const float nv = fmaf(v, E, tv);                                       \
    const float nJv0 = fmaf(E, Jv0, g * Ju0);                              \
    const float nJv1 = fmaf(E, Jv1, g * Ju1);                              \
    const float tu0 = Ju0, tu1 = Ju1, tu = u;                              \
    Ju0 = nJv0; Ju1 = nJv1; u = nv;                                        \
    Jv0 = tu0;  Jv1 = tu1;  v = tu;                                        \
  }

  const int gid = blockIdx.x * BLOCK + tid;
  const int lidx = gid < npts ? gid : 0;
  const float2 xi = ((const float2*)x)[lidx];
  float u = xi.x, v = xi.y;
  float Ju0 = 1.0f, Ju1 = 0.0f;
  float Jv0 = 0.0f, Jv1 = 1.0f;
  for (int l = 0; l < NL; ++l) {
    LAYER_STEP(l * NNODE, u, v, Ju0, Ju1, Jv0, Jv1);
  }
#undef LAYER_STEP

  const float au = a_in[0], av = a_in[1];
  const float d0 = u - au, d1 = v - av;
  const float G00 = fmaf(Ju0, Ju0, Jv0 * Jv0);
  const float G01 = fmaf(Ju0, Ju1, Jv0 * Jv1);
  const float G11 = fmaf(Ju1, Ju1, Jv1 * Jv1);
  const float detJ = Ju0 * Jv1 - Ju1 * Jv0;
  const float inv_det = 1.0f / (detJ * detJ);  // det(G) = det(J)^2
  const float o0 = -(G11 * d0 - G01 * d1) * inv_det;
  const float o1 = -(G00 * d1 - G01 * d0) * inv_det;
  if (gid < npts) {
    ((float2*)out)[gid] = make_float2(o0, o1);
  }
}

extern "C" void kernel_launch(void* const* d_in, const int* in_sizes, int n_in,
                              void* d_out, int out_size, void* d_ws, size_t ws_size,
                              hipStream_t stream) {
  const float* x       = (const float*)d_in[0];
  const float* centers = (const float*)d_in[1];
  const float* Ws      = (const float*)d_in[2];
  const float* Wt      = (const float*)d_in[3];
  const float* attr    = (const float*)d_in[4];
  const float* sigma   = (const float*)d_in[5];
  float* out = (float*)d_out;
  float4* T = (float4*)d_ws;                       // 41120 B table
  float* a_ws = (float*)((char*)d_ws + sizeof(float4) * NENT);  // a[2]

  const int npts = in_sizes[0] / 2;
  const int blocks = (npts + BLOCK - 1) / BLOCK;

  build_table<<<(NENT + 255) / 256, 256, 0, stream>>>(centers, Ws, Wt, sigma, T);
  attractor_kernel<<<1, 64, 0, stream>>>(centers, Ws, Wt, attr, sigma, a_ws);
  dynamics_kernel<<<blocks, BLOCK, 0, stream>>>(x, T, a_ws, out, npts);
}